// Round 4
// baseline (2757.854 us; speedup 1.0000x reference)
//
#include <hip/hip_runtime.h>
#include <math.h>

#define NMAT 50000
#define MPB 8                    // matrices per block: 256 thr = 4 waves = 8 half-waves
#define NBLK (NMAT / MPB)        // 6250

__device__ __forceinline__ float frcp(float x)  { return __builtin_amdgcn_rcpf(x); }
__device__ __forceinline__ float frsq(float x)  { return __builtin_amdgcn_rsqf(x); }
__device__ __forceinline__ float fsqrt_(float x){ return __builtin_amdgcn_sqrtf(x); }

// x + rotate-right within rows of 16 (VALU pipe, not LDS pipe)
#define DPP_ROR_ADD(x, ctrl) \
  ((x) + __int_as_float(__builtin_amdgcn_update_dpp(0, __float_as_int(x), (ctrl), 0xF, 0xF, false)))

// sum across the 32-lane half-wave, all lanes get the result
__device__ __forceinline__ float red32(float x) {
  x = DPP_ROR_ADD(x, 0x121);   // row_ror:1
  x = DPP_ROR_ADD(x, 0x122);   // row_ror:2
  x = DPP_ROR_ADD(x, 0x124);   // row_ror:4
  x = DPP_ROR_ADD(x, 0x128);   // row_ror:8
  x += __shfl_xor(x, 16, 32);
  return x;
}

__device__ __forceinline__ float f4c(const float4& v, int e) {
  return e == 0 ? v.x : e == 1 ? v.y : e == 2 ? v.z : v.w;   // e compile-time
}

__global__ __launch_bounds__(256, 2) void riem_batch(const float* __restrict__ X,
                                                     const float* __restrict__ Y,
                                                     float* __restrict__ partial) {
  const int tid = threadIdx.x;
  const int c   = tid & 31;        // column owned by this lane
  const int hw  = tid >> 5;        // half-wave id (0..7)
  const long mat = (long)blockIdx.x * MPB + hw;
  const float* Yp = Y + mat * 1024;
  const float* Xp = X + mat * 1024;

  // 128 B broadcast lines per matrix (half-wave private, wave-ordered LDS: no barriers)
  __shared__ __align__(16) float tb[MPB][32];   // multipliers t / HH vector v / dsv
  __shared__ __align__(16) float xb[MPB][32];   // X row j / HH vector q
  __shared__ __align__(16) float db[MPB][32];   // tridiag diagonal
  __shared__ __align__(16) float eb[MPB][32];   // eb[i] = e2[i-1], eb[0]=0
  __shared__ float psum[MPB];
  float* tp = tb[hw];
  float* xp = xb[hw];
  float* dp = db[hw];
  float* ep = eb[hw];

  float y[32], x[32];
#pragma unroll
  for (int i = 0; i < 32; ++i) y[i] = Yp[i * 32 + c];
#pragma unroll
  for (int i = 0; i < 32; ++i) x[i] = Xp[i * 32 + c];

  // ---- simultaneous congruence: Y -> D (LDL pivots), X -> L^{-1} X L^{-T} ----
  // per step j:  X' = X - w xj^T - (Xrow_j - w*xjj)^T w^T pattern, w_i = t_i (i>j)
  float dc = 0.0f;
#pragma unroll
  for (int j = 0; j < 31; ++j) {
    float piv  = __shfl(y[j], j, 32);          // pivot D[j], uniform per half-wave
    float rinv = frcp(piv);
    if (c == j) dc = y[j];
    float t  = (c > j) ? y[j] * rinv : 0.0f;   // w_c (0 on frozen columns)
    tp[c] = t;                                 // broadcast multipliers
    xp[c] = x[j];                              // broadcast row j of X (symmetric)
    float xjj = __shfl(x[j], j, 32);
    float yj = y[j], xj = x[j];
#pragma unroll
    for (int g = 0; g < 8; ++g) {
      float4 X4 = *(const float4*)(xp + 4 * g);
      if (4 * g + 3 <= j) {                    // whole group i<=j: col-part only
#pragma unroll
        for (int e = 0; e < 4; ++e)
          x[4 * g + e] = fmaf(-t, f4c(X4, e), x[4 * g + e]);
      } else {
        float4 T4 = *(const float4*)(tp + 4 * g);
#pragma unroll
        for (int e = 0; e < 4; ++e) {
          const int i = 4 * g + e;
          float u;
          if (i <= j) {
            u = f4c(X4, e);                    // w_i = 0
          } else {
            u = fmaf(-f4c(T4, e), xjj, f4c(X4, e));
            y[i] = fmaf(-f4c(T4, e), yj, y[i]);    // Y Schur complement
            x[i] = fmaf(-f4c(T4, e), xj, x[i]);    // row part
          }
          x[i] = fmaf(-t, u, x[i]);                // col part
        }
      }
    }
  }
  if (c == 31) dc = y[31];
  float dsv = frsq(dc);                        // D[c]^{-1/2}
  // y[] dead from here

  // ---- A = D^{-1/2} (L^{-1} X L^{-T}) D^{-1/2} ----
  tp[c] = dsv;
#pragma unroll
  for (int g = 0; g < 8; ++g) {
    float4 D4 = *(const float4*)(tp + 4 * g);
#pragma unroll
    for (int e = 0; e < 4; ++e) x[4 * g + e] *= f4c(D4, e) * dsv;
  }

  // ---- Householder tridiagonalization; d/e2 -> LDS (keeps register peak low) ----
  float e2max = 0.0f, dminv = 1e30f, dmaxv = -1e30f;
  if (c == 0) ep[0] = 0.0f;
#pragma unroll
  for (int k = 0; k < 30; ++k) {
    float colv = x[k];
    float dkk  = __shfl(x[k], k, 32);          // A[k][k], final at step k
    if (c == 0) dp[k] = dkk;
    dminv = fminf(dminv, dkk); dmaxv = fmaxf(dmaxv, dkk);
    float sq    = (c > k) ? colv * colv : 0.0f;
    float sigma = red32(sq);                   // ||A[k+1:,k]||^2
    float akk1  = __shfl(x[k], k + 1, 32);
    if (c == 0) ep[k + 1] = sigma;             // e2[k]
    e2max = fmaxf(e2max, sigma);
    float nrm   = fsqrt_(sigma);
    float alpha = (akk1 >= 0.0f) ? -nrm : nrm;
    float denom = fmaf(-alpha, akk1, sigma);   // vTv/2
    float tau   = frcp(fmaxf(denom, 1e-35f));  // sigma==0 -> v==0 no-op
    float v     = (c == k + 1) ? (akk1 - alpha) : ((c > k + 1) ? colv : 0.0f);
    tp[c] = v;                                 // broadcast v
    float acc = 0.0f;
#pragma unroll
    for (int g = 0; g < 8; ++g) {              // acc_c = sum_j A[j][c] v_j
      if (4 * g + 3 <= k) continue;
      float4 V4 = *(const float4*)(tp + 4 * g);
#pragma unroll
      for (int e = 0; e < 4; ++e) {
        int j = 4 * g + e;
        if (j > k) acc = fmaf(x[j], f4c(V4, e), acc);
      }
    }
    float p = tau * acc;
    float K = 0.5f * tau * red32(v * p);
    float q = fmaf(-K, v, p);
    xp[c] = q;                                 // broadcast q
#pragma unroll
    for (int g = 0; g < 8; ++g) {              // A -= v q^T + q v^T
      if (4 * g + 3 <= k) continue;
      float4 V4 = *(const float4*)(tp + 4 * g);
      float4 Q4 = *(const float4*)(xp + 4 * g);
#pragma unroll
      for (int e = 0; e < 4; ++e) {
        int j = 4 * g + e;
        if (j > k) x[j] = fmaf(-v, f4c(Q4, e), fmaf(-q, f4c(V4, e), x[j]));
      }
    }
  }
  {
    float d30 = __shfl(x[30], 30, 32);
    float d31 = __shfl(x[31], 31, 32);
    float el  = __shfl(x[30], 31, 32);         // trailing subdiagonal
    if (c == 0) { dp[30] = d30; dp[31] = d31; ep[31] = el * el; }
    e2max = fmaxf(e2max, el * el);
    dminv = fminf(dminv, fminf(d30, d31));
    dmaxv = fmaxf(dmaxv, fmaxf(d30, d31));
  }
  // x[] dead from here — NOW pull d/e2 into registers (peak live stays at elim phase)

  float drg[32], erg[32];
#pragma unroll
  for (int g = 0; g < 8; ++g) {
    float4 D4 = *(const float4*)(dp + 4 * g);
    float4 E4 = *(const float4*)(ep + 4 * g);
#pragma unroll
    for (int e = 0; e < 4; ++e) { drg[4 * g + e] = f4c(D4, e); erg[4 * g + e] = f4c(E4, e); }
  }

  // ---- Gershgorin bounds ----
  float rad = 2.0f * fsqrt_(e2max);
  float lo = fmaxf(dminv - rad, 1e-3f);
  float hi = dmaxv + rad;

  // ---- bisection with Sturm counts: lane c -> eigenvalue #c (pure VALU) ----
  // 14 iters: lambda err <= ~12/2^15 ~ 3.7e-4; per-matrix d err ~1e-3, random sign,
  // averaged over 50k matrices -> negligible vs 7.6e-2 threshold.
  for (int it = 0; it < 14; ++it) {
    float mid = 0.5f * (lo + hi);
    float qq = drg[0] - mid;
    qq = (fabsf(qq) < 1e-30f) ? -1e-30f : qq;
    int cnt = (qq < 0.0f) ? 1 : 0;
#pragma unroll
    for (int i = 1; i < 32; ++i) {
      qq = (drg[i] - mid) - erg[i] * frcp(qq);
      qq = (fabsf(qq) < 1e-30f) ? -1e-30f : qq;     // pivmin clamp
      cnt += (qq < 0.0f) ? 1 : 0;
    }
    bool le = (cnt <= c);
    lo = le ? mid : lo;
    hi = le ? hi : mid;
  }

  float lam = 0.5f * (lo + hi);
  float lg  = __logf(lam);
  float s   = red32(lg * lg);
  float dd  = fsqrt_(s);                 // d(x_b, y_b)

  if (c == 0) psum[hw] = dd;
  __syncthreads();
  if (tid == 0) {
    float tsum = 0.0f;
#pragma unroll
    for (int i = 0; i < MPB; ++i) tsum += psum[i];
    partial[blockIdx.x] = tsum;
  }
}

__global__ __launch_bounds__(256) void riem_finish(const float* __restrict__ partial,
                                                   float* __restrict__ out) {
  float acc = 0.0f;
  for (int i = threadIdx.x; i < NBLK; i += 256) acc += partial[i];
  acc += __shfl_xor(acc, 1);
  acc += __shfl_xor(acc, 2);
  acc += __shfl_xor(acc, 4);
  acc += __shfl_xor(acc, 8);
  acc += __shfl_xor(acc, 16);
  acc += __shfl_xor(acc, 32);
  __shared__ float ps[4];
  if ((threadIdx.x & 63) == 0) ps[threadIdx.x >> 6] = acc;
  __syncthreads();
  if (threadIdx.x == 0)
    out[0] = (ps[0] + ps[1] + ps[2] + ps[3]) * (1.0f / (float)NMAT);
}

extern "C" void kernel_launch(void* const* d_in, const int* in_sizes, int n_in,
                              void* d_out, int out_size, void* d_ws, size_t ws_size,
                              hipStream_t stream) {
  const float* x = (const float*)d_in[0];
  const float* y = (const float*)d_in[1];
  float* out  = (float*)d_out;
  float* part = (float*)d_ws;   // NBLK floats = 25 KB
  riem_batch<<<NBLK, 256, 0, stream>>>(x, y, part);
  riem_finish<<<1, 256, 0, stream>>>(part, out);
}